// Round 1
// baseline (1876.769 us; speedup 1.0000x reference)
//
#include <hip/hip_runtime.h>
#include <hip/hip_bf16.h>
#include <stdint.h>

// ---------------------------------------------------------------------------
// ScRegNet GCN pretrainer fused pipeline, MI355X / gfx950.
// h0 = relu(adj@(x@W0)+b0); h1 = relu(adj@(h0@W1)+b1); emb = adj@(h1@W2)+b2
// logits = gelu(concat(emb[tf],emb[gene])@Wh1+bh1)@Wh2+bh2
// Strategy: bf16 MFMA (16x16x32) for every GEMM, fp32 accumulate + fp32
// epilogues. m97-style 128x128 tile, BK=32, 4 waves, global_load_lds staging.
// ---------------------------------------------------------------------------

using f32x4  = __attribute__((ext_vector_type(4))) float;
using bf16x8 = __attribute__((ext_vector_type(8))) __bf16;
using u16x8  = __attribute__((ext_vector_type(8))) unsigned short;
using u16x4  = __attribute__((ext_vector_type(4))) unsigned short;

static __device__ __forceinline__ unsigned short f2bf(float f) {
  unsigned u = __builtin_bit_cast(unsigned, f);
  u += 0x7FFFu + ((u >> 16) & 1u);           // RNE (finite inputs only)
  return (unsigned short)(u >> 16);
}
static __device__ __forceinline__ float bf2f(unsigned short h) {
  unsigned u = ((unsigned)h) << 16;
  return __builtin_bit_cast(float, u);
}
// async global->LDS, 16 B per lane. LDS dest: wave-uniform base + lane*16.
static __device__ __forceinline__ void gload_lds16(const void* g, void* l) {
  __builtin_amdgcn_global_load_lds((__attribute__((address_space(1))) void*)(void*)g,
                                   (__attribute__((address_space(3))) void*)l,
                                   16, 0, 0);
}

// --------------------------- small converters ------------------------------

// out[nf][k] = bf16(in[k][nf])   (weights: [K][Nf] fp32 -> [Nf][K] bf16)
__global__ void tcvt_kernel(const float* __restrict__ in,
                            unsigned short* __restrict__ outp, int K, int Nf) {
  int id = blockIdx.x * 256 + threadIdx.x;
  if (id >= K * Nf) return;
  int k = id % K, nf = id / K;
  outp[id] = f2bf(in[(size_t)k * Nf + nf]);
}

// flat fp32 -> bf16 (adj copy), vectorized 8/thread
__global__ void cvt_bf16_kernel(const float* __restrict__ in,
                                unsigned short* __restrict__ outp, size_t n) {
  size_t i = ((size_t)blockIdx.x * blockDim.x + threadIdx.x) * 8;
  size_t stride = (size_t)gridDim.x * blockDim.x * 8;
  for (; i + 8 <= n; i += stride) {
    const float4* p = (const float4*)(in + i);
    float4 a = p[0], b = p[1];
    u16x8 v;
    v[0] = f2bf(a.x); v[1] = f2bf(a.y); v[2] = f2bf(a.z); v[3] = f2bf(a.w);
    v[4] = f2bf(b.x); v[5] = f2bf(b.y); v[6] = f2bf(b.z); v[7] = f2bf(b.w);
    *(u16x8*)(outp + i) = v;
  }
}

// ------------------------------ main GEMM ----------------------------------
// C(MxN) = A(MxK) * Bt(NxK)^T ; 128x128 tile, BK=32, 256 thr = 4 waves (2x2),
// each wave 64x64 = 4x4 fragments of mfma_f32_16x16x32_bf16.
// EP: 0 -> Cout bf16 [N][M] (transposed, no bias)        (feeds next B^T)
//     1 -> Cout fp32 [M][N] = relu(acc + bias[n])        (feeds next A)
//     2 -> Cout bf16 [M][N] = acc + bias[n]              (EMB for gather)
// ABF16: A is bf16 [M][K] (global_load_lds) vs fp32 [M][K] (reg-stage cvt).
template <int EP, bool ABF16>
__global__ __launch_bounds__(256, 2)
void gemm_bt(const void* __restrict__ Av, const unsigned short* __restrict__ Bt,
             void* __restrict__ Cout, const float* __restrict__ bias,
             int M, int N, int K) {
  __shared__ __align__(16) unsigned short As[128 * 32];
  __shared__ __align__(16) unsigned short Bs[128 * 32];
  const int t = threadIdx.x;
  const int l = t & 63;
  const int w = t >> 6;
  const int nb = blockIdx.x, mb = blockIdx.y;
  const int wr = w >> 1, wc = w & 1;

  f32x4 acc[4][4] = {};

  // staging geometry for global_load_lds (2 instrs cover 8 KiB tile):
  // instr i: LDS byte = i*4096 + w*1024 + l*16 -> row = i*64+w*16+(l>>2),
  //          k0 = (l&3)*8
  const int srow = w * 16 + (l >> 2);
  const int sk0  = (l & 3) * 8;
  const unsigned short* Bg = Bt + (size_t)(nb * 128 + srow) * K + sk0;
  unsigned short* BsL = Bs + (size_t)w * 512 + (size_t)l * 8;
  unsigned short* AsL = As + (size_t)w * 512 + (size_t)l * 8;

  const unsigned short* Ag16 = nullptr;
  const float* Ag32 = nullptr;
  const int ar = t >> 1;           // fp32 path: row in tile
  const int ak = (t & 1) * 16;     // fp32 path: k offset
  unsigned short* AsW = As + ar * 32 + ak;
  if constexpr (ABF16) {
    Ag16 = (const unsigned short*)Av + (size_t)(mb * 128 + srow) * K + sk0;
  } else {
    Ag32 = (const float*)Av + (size_t)(mb * 128 + ar) * K + ak;
  }

  const int steps = K >> 5;
  for (int kb = 0; kb < steps; ++kb) {
    gload_lds16(Bg, BsL);
    gload_lds16(Bg + (size_t)64 * K, BsL + 2048);
    Bg += 32;
    if constexpr (ABF16) {
      gload_lds16(Ag16, AsL);
      gload_lds16(Ag16 + (size_t)64 * K, AsL + 2048);
      Ag16 += 32;
    } else {
      const float4* p = (const float4*)Ag32;
      float4 a0 = p[0], a1 = p[1], a2 = p[2], a3 = p[3];
      u16x8 v0, v1;
      v0[0] = f2bf(a0.x); v0[1] = f2bf(a0.y); v0[2] = f2bf(a0.z); v0[3] = f2bf(a0.w);
      v0[4] = f2bf(a1.x); v0[5] = f2bf(a1.y); v0[6] = f2bf(a1.z); v0[7] = f2bf(a1.w);
      v1[0] = f2bf(a2.x); v1[1] = f2bf(a2.y); v1[2] = f2bf(a2.z); v1[3] = f2bf(a2.w);
      v1[4] = f2bf(a3.x); v1[5] = f2bf(a3.y); v1[6] = f2bf(a3.z); v1[7] = f2bf(a3.w);
      *(u16x8*)AsW = v0;
      *(u16x8*)(AsW + 8) = v1;
      Ag32 += 32;
    }
    __syncthreads();

    bf16x8 af[4], bfr[4];
#pragma unroll
    for (int mi = 0; mi < 4; ++mi)
      af[mi] = *(const bf16x8*)&As[(wr * 64 + mi * 16 + (l & 15)) * 32 + (l >> 4) * 8];
#pragma unroll
    for (int ni = 0; ni < 4; ++ni)
      bfr[ni] = *(const bf16x8*)&Bs[(wc * 64 + ni * 16 + (l & 15)) * 32 + (l >> 4) * 8];
#pragma unroll
    for (int mi = 0; mi < 4; ++mi)
#pragma unroll
      for (int ni = 0; ni < 4; ++ni)
        acc[mi][ni] = __builtin_amdgcn_mfma_f32_16x16x32_bf16(af[mi], bfr[ni],
                                                              acc[mi][ni], 0, 0, 0);
    __syncthreads();
  }

  // epilogue: C/D layout (m89/m91-verified): col = lane&15, row = (lane>>4)*4+r
  const int r0 = (l >> 4) * 4;
  const int c0 = l & 15;
  const int growb = mb * 128 + wr * 64 + r0;
  const int gcolb = nb * 128 + wc * 64 + c0;
  if constexpr (EP == 0) {
    unsigned short* Ct = (unsigned short*)Cout;  // [N][M]
#pragma unroll
    for (int ni = 0; ni < 4; ++ni) {
      int col = gcolb + ni * 16;
#pragma unroll
      for (int mi = 0; mi < 4; ++mi) {
        int row = growb + mi * 16;
        f32x4 v = acc[mi][ni];
        u16x4 o;
        o[0] = f2bf(v[0]); o[1] = f2bf(v[1]); o[2] = f2bf(v[2]); o[3] = f2bf(v[3]);
        *(u16x4*)&Ct[(size_t)col * M + row] = o;
      }
    }
  } else if constexpr (EP == 1) {
    float* C = (float*)Cout;  // [M][N]
#pragma unroll
    for (int ni = 0; ni < 4; ++ni) {
      int col = gcolb + ni * 16;
      float b = bias[col];
#pragma unroll
      for (int mi = 0; mi < 4; ++mi) {
        int row = growb + mi * 16;
        f32x4 v = acc[mi][ni];
#pragma unroll
        for (int r = 0; r < 4; ++r)
          C[(size_t)(row + r) * N + col] = fmaxf(v[r] + b, 0.0f);
      }
    }
  } else {
    unsigned short* C = (unsigned short*)Cout;  // [M][N] bf16
#pragma unroll
    for (int ni = 0; ni < 4; ++ni) {
      int col = gcolb + ni * 16;
      float b = bias[col];
#pragma unroll
      for (int mi = 0; mi < 4; ++mi) {
        int row = growb + mi * 16;
        f32x4 v = acc[mi][ni];
#pragma unroll
        for (int r = 0; r < 4; ++r)
          C[(size_t)(row + r) * N + col] = f2bf(v[r] + b);
      }
    }
  }
}

// ------------------------------ head kernel --------------------------------
// Block: 64 pairs x 256 cols, 4 waves each owning a 64-col slab.
// A-tile gathered from EMB (bf16 [16384][256]) via per-lane global_load_lds.
// Fused: bias + exact GELU -> hdn LDS (stride 258, conflict-free) -> 3-logit dot.
__global__ __launch_bounds__(256, 2)
void head_kernel(const unsigned short* __restrict__ EMB, const int* __restrict__ tf,
                 const int* __restrict__ gi, const unsigned short* __restrict__ Wh1t,
                 const float* __restrict__ bh1, const float* __restrict__ Wh2,
                 const float* __restrict__ bh2, float* __restrict__ out, int P) {
  __shared__ __align__(16) unsigned short As[64 * 32];
  __shared__ __align__(16) unsigned short Bs[256 * 32];
  __shared__ __align__(16) unsigned short hdn[64 * 258];
  __shared__ float wh2s[256 * 3];
  const int t = threadIdx.x, l = t & 63, w = t >> 6;
  const int pb = blockIdx.x;

  wh2s[t]       = Wh2[t];
  wh2s[t + 256] = Wh2[t + 256];
  wh2s[t + 512] = Wh2[t + 512];

  const int arow = w * 16 + (l >> 2);          // pair-local row this lane stages
  int p = pb * 64 + arow;
  if (p >= P) p = P - 1;                       // clamp (writes masked later)
  const size_t tfo = (size_t)tf[p] * 256;
  const size_t gio = (size_t)gi[p] * 256;
  const int ak0 = (l & 3) * 8;
  const unsigned short* BgBase = Wh1t + (size_t)(w * 64 + (l >> 2)) * 512 + ak0;
  unsigned short* AsL = As + (size_t)w * 512 + (size_t)l * 8;
  unsigned short* BsL = Bs + (size_t)w * 2048 + (size_t)l * 8;

  f32x4 acc[4][4] = {};
  for (int kb = 0; kb < 16; ++kb) {
    int kg = kb * 32 + ak0;  // concat K: [0,256)=tf half, [256,512)=gene half
    const unsigned short* ag = EMB + ((kg < 256) ? (tfo + kg) : (gio + (kg - 256)));
    gload_lds16(ag, AsL);
    const unsigned short* bg = BgBase + kb * 32;
#pragma unroll
    for (int i = 0; i < 4; ++i)
      gload_lds16(bg + (size_t)i * 16 * 512, BsL + i * 512);
    __syncthreads();

    bf16x8 af[4], bfr[4];
#pragma unroll
    for (int mi = 0; mi < 4; ++mi)
      af[mi] = *(const bf16x8*)&As[(mi * 16 + (l & 15)) * 32 + (l >> 4) * 8];
#pragma unroll
    for (int ni = 0; ni < 4; ++ni)
      bfr[ni] = *(const bf16x8*)&Bs[(w * 64 + ni * 16 + (l & 15)) * 32 + (l >> 4) * 8];
#pragma unroll
    for (int mi = 0; mi < 4; ++mi)
#pragma unroll
      for (int ni = 0; ni < 4; ++ni)
        acc[mi][ni] = __builtin_amdgcn_mfma_f32_16x16x32_bf16(af[mi], bfr[ni],
                                                              acc[mi][ni], 0, 0, 0);
    __syncthreads();
  }

  // bias + exact GELU -> hdn[row][col], row stride 258 (bank-conflict-free)
  const int r0 = (l >> 4) * 4, c0 = l & 15;
#pragma unroll
  for (int ni = 0; ni < 4; ++ni) {
    int col = w * 64 + ni * 16 + c0;
    float b = bh1[col];
#pragma unroll
    for (int mi = 0; mi < 4; ++mi) {
      int row = mi * 16 + r0;
      f32x4 v = acc[mi][ni];
#pragma unroll
      for (int r = 0; r < 4; ++r) {
        float xv = v[r] + b;
        float g = 0.5f * xv * (1.0f + erff(xv * 0.70710678118f));
        hdn[(row + r) * 258 + col] = f2bf(g);
      }
    }
  }
  __syncthreads();

  if (t < 64) {
    int pg = pb * 64 + t;
    if (pg < P) {
      float a0 = bh2[0], a1 = bh2[1], a2 = bh2[2];
      const unsigned short* hr = hdn + t * 258;
      for (int k = 0; k < 256; ++k) {
        float h = bf2f(hr[k]);
        a0 = fmaf(h, wh2s[k * 3 + 0], a0);
        a1 = fmaf(h, wh2s[k * 3 + 1], a1);
        a2 = fmaf(h, wh2s[k * 3 + 2], a2);
      }
      out[(size_t)pg * 3 + 0] = a0;
      out[(size_t)pg * 3 + 1] = a1;
      out[(size_t)pg * 3 + 2] = a2;
    }
  }
}

// ------------------------------- launcher ----------------------------------

extern "C" void kernel_launch(void* const* d_in, const int* in_sizes, int n_in,
                              void* d_out, int out_size, void* d_ws, size_t ws_size,
                              hipStream_t stream) {
  const float* x   = (const float*)d_in[0];
  const float* adj = (const float*)d_in[1];
  const int*   tf  = (const int*)d_in[2];
  const int*   gi  = (const int*)d_in[3];
  const float* W0  = (const float*)d_in[4];
  const float* b0  = (const float*)d_in[5];
  const float* W1  = (const float*)d_in[6];
  const float* b1  = (const float*)d_in[7];
  const float* W2  = (const float*)d_in[8];
  const float* b2  = (const float*)d_in[9];
  const float* Wh1 = (const float*)d_in[10];
  const float* bh1 = (const float*)d_in[11];
  const float* Wh2 = (const float*)d_in[12];
  const float* bh2 = (const float*)d_in[13];
  float* out = (float*)d_out;

  const int N_NODES = 16384;
  const int P = in_sizes[2];  // 100000

  char* ws = (char*)d_ws;
  size_t off = 0;
  auto alloc = [&](size_t bytes) -> char* {
    char* p = ws + off;
    off += (bytes + 255) & ~(size_t)255;
    return p;
  };
  unsigned short* W0t  = (unsigned short*)alloc((size_t)512 * 1024 * 2);
  unsigned short* W1t  = (unsigned short*)alloc((size_t)512 * 512 * 2);
  unsigned short* W2t  = (unsigned short*)alloc((size_t)256 * 512 * 2);
  unsigned short* Wh1t = (unsigned short*)alloc((size_t)256 * 512 * 2);
  unsigned short* Tt   = (unsigned short*)alloc((size_t)512 * N_NODES * 2); // T0t/T1t/T2t
  float*          H    = (float*)alloc((size_t)N_NODES * 512 * 4);          // H0/H1
  unsigned short* EMB  = (unsigned short*)alloc((size_t)N_NODES * 256 * 2);
  size_t base_end = off;

  bool useAdjB = false;
  unsigned short* adjb = nullptr;
  if (ws_size >= base_end + (size_t)N_NODES * N_NODES * 2) {
    adjb = (unsigned short*)alloc((size_t)N_NODES * N_NODES * 2);
    useAdjB = true;
  }

  // weight transpose+convert (tiny)
  tcvt_kernel<<<dim3((1024 * 512 + 255) / 256), 256, 0, stream>>>(W0, W0t, 1024, 512);
  tcvt_kernel<<<dim3((512 * 512 + 255) / 256), 256, 0, stream>>>(W1, W1t, 512, 512);
  tcvt_kernel<<<dim3((512 * 256 + 255) / 256), 256, 0, stream>>>(W2, W2t, 512, 256);
  tcvt_kernel<<<dim3((512 * 256 + 255) / 256), 256, 0, stream>>>(Wh1, Wh1t, 512, 256);
  if (useAdjB)
    cvt_bf16_kernel<<<4096, 256, 0, stream>>>(adj, adjb, (size_t)N_NODES * N_NODES);

  // G1: T0t = (x @ W0)^T                       [512][16384] bf16
  gemm_bt<0, false><<<dim3(4, 128), 256, 0, stream>>>(x, W0t, Tt, nullptr,
                                                      N_NODES, 512, 1024);
  // G2: H0 = relu(adj @ T0 + b0)               [16384][512] fp32
  if (useAdjB)
    gemm_bt<1, true><<<dim3(4, 128), 256, 0, stream>>>(adjb, Tt, H, b0,
                                                       N_NODES, 512, N_NODES);
  else
    gemm_bt<1, false><<<dim3(4, 128), 256, 0, stream>>>(adj, Tt, H, b0,
                                                        N_NODES, 512, N_NODES);
  // G3: T1t = (H0 @ W1)^T
  gemm_bt<0, false><<<dim3(4, 128), 256, 0, stream>>>(H, W1t, Tt, nullptr,
                                                      N_NODES, 512, 512);
  // G4: H1 = relu(adj @ T1 + b1)
  if (useAdjB)
    gemm_bt<1, true><<<dim3(4, 128), 256, 0, stream>>>(adjb, Tt, H, b1,
                                                       N_NODES, 512, N_NODES);
  else
    gemm_bt<1, false><<<dim3(4, 128), 256, 0, stream>>>(adj, Tt, H, b1,
                                                        N_NODES, 512, N_NODES);
  // G5: T2t = (H1 @ W2)^T                      [256][16384] bf16
  gemm_bt<0, false><<<dim3(2, 128), 256, 0, stream>>>(H, W2t, Tt, nullptr,
                                                      N_NODES, 256, 512);
  // G6: EMB = adj @ T2 + b2                    [16384][256] bf16
  if (useAdjB)
    gemm_bt<2, true><<<dim3(2, 128), 256, 0, stream>>>(adjb, Tt, EMB, b2,
                                                       N_NODES, 256, N_NODES);
  else
    gemm_bt<2, false><<<dim3(2, 128), 256, 0, stream>>>(adj, Tt, EMB, b2,
                                                        N_NODES, 256, N_NODES);
  // head: gather + MLP + logits
  head_kernel<<<dim3((P + 63) / 64), 256, 0, stream>>>(EMB, tf, gi, Wh1t, bh1,
                                                       Wh2, bh2, out, P);
}

// Round 3
// 1344.120 us; speedup vs baseline: 1.3963x; 1.3963x over previous
//
#include <hip/hip_runtime.h>
#include <hip/hip_bf16.h>
#include <stdint.h>

// ---------------------------------------------------------------------------
// ScRegNet GCN pretrainer fused pipeline, MI355X / gfx950.  Round 3 (= R2
// resubmit; R2 bench died on infra before running).
// h0 = relu(adj@(x@W0)+b0); h1 = relu(adj@(h0@W1)+b1); emb = adj@(h1@W2)+b2
// logits = gelu(concat(emb[tf],emb[gene])@Wh1+bh1)@Wh2+bh2
//
// R1 -> R2 changes (theory: 2-phase critical path = stage+barrier drain):
//  - BK 32 -> 64: halves barriers per K; 32 MFMA per barrier pair.
//  - 16B-slot XOR swizzle (rule #21: linear gload_lds dest + inverse-swizzled
//    GLOBAL source + swizzled read) to kill the 16-way ds_read_b128 conflict
//    a 128B-stride row-major tile would have.
//  - XCD-chunked block swizzle (T1) on all GEMMs (nwg % 8 == 0).
//  - G6 split-K=2 (was 256 blocks = 1/CU) + tiny reduce+bias kernel.
//  - H stored bf16 -> G3/G5 use the global_load_lds A path.
//  - head: BK=64, union'd LDS (43 KiB), wave-parallel K-split tail.
// ---------------------------------------------------------------------------

using f32x4  = __attribute__((ext_vector_type(4))) float;
using bf16x8 = __attribute__((ext_vector_type(8))) __bf16;
using u16x8  = __attribute__((ext_vector_type(8))) unsigned short;
using u16x4  = __attribute__((ext_vector_type(4))) unsigned short;

static __device__ __forceinline__ unsigned short f2bf(float f) {
  unsigned u = __builtin_bit_cast(unsigned, f);
  u += 0x7FFFu + ((u >> 16) & 1u);           // RNE (finite inputs only)
  return (unsigned short)(u >> 16);
}
static __device__ __forceinline__ float bf2f(unsigned short h) {
  unsigned u = ((unsigned)h) << 16;
  return __builtin_bit_cast(float, u);
}
// async global->LDS, 16 B per lane. LDS dest: wave-uniform base + lane*16.
static __device__ __forceinline__ void gload_lds16(const void* g, void* l) {
  __builtin_amdgcn_global_load_lds((__attribute__((address_space(1))) void*)(void*)g,
                                   (__attribute__((address_space(3))) void*)l,
                                   16, 0, 0);
}

// --------------------------- small converters ------------------------------

// out[nf][k] = bf16(in[k][nf])   (weights: [K][Nf] fp32 -> [Nf][K] bf16)
__global__ void tcvt_kernel(const float* __restrict__ in,
                            unsigned short* __restrict__ outp, int K, int Nf) {
  int id = blockIdx.x * 256 + threadIdx.x;
  if (id >= K * Nf) return;
  int k = id % K, nf = id / K;
  outp[id] = f2bf(in[(size_t)k * Nf + nf]);
}

// flat fp32 -> bf16 (adj copy), vectorized 8/thread
__global__ void cvt_bf16_kernel(const float* __restrict__ in,
                                unsigned short* __restrict__ outp, size_t n) {
  size_t i = ((size_t)blockIdx.x * blockDim.x + threadIdx.x) * 8;
  size_t stride = (size_t)gridDim.x * blockDim.x * 8;
  for (; i + 8 <= n; i += stride) {
    const float4* p = (const float4*)(in + i);
    float4 a = p[0], b = p[1];
    u16x8 v;
    v[0] = f2bf(a.x); v[1] = f2bf(a.y); v[2] = f2bf(a.z); v[3] = f2bf(a.w);
    v[4] = f2bf(b.x); v[5] = f2bf(b.y); v[6] = f2bf(b.z); v[7] = f2bf(b.w);
    *(u16x8*)(outp + i) = v;
  }
}

// split-K=2 reduce + bias -> bf16   (EMB = P[0] + P[1] + bias)
__global__ void reduce2_kernel(const float* __restrict__ Pp, const float* __restrict__ bias,
                               unsigned short* __restrict__ outp, int MN, int Nf) {
  int i = (blockIdx.x * 256 + threadIdx.x) * 4;
  if (i >= MN) return;
  float4 a = *(const float4*)(Pp + i);
  float4 b = *(const float4*)(Pp + MN + i);
  int col = i & (Nf - 1);
  u16x4 o;
  o[0] = f2bf(a.x + b.x + bias[col + 0]);
  o[1] = f2bf(a.y + b.y + bias[col + 1]);
  o[2] = f2bf(a.z + b.z + bias[col + 2]);
  o[3] = f2bf(a.w + b.w + bias[col + 3]);
  *(u16x4*)(outp + i) = o;
}

// ------------------------------ main GEMM ----------------------------------
// C(MxN) = A(MxK) * Bt(NxK)^T ; 128x128 tile, BK=64, 256 thr = 4 waves (2x2),
// each wave 64x64 = 4x4 frags of mfma_f32_16x16x32_bf16, 2 k-slices per step.
// LDS tile layout (both A and B): elem(row,k) at row*64 + (k ^ ((row&7)<<3))
//  -> stage source k0 = 8*((l&7)^(l>>3)) (linear dest, pre-swizzled source);
//  -> read XOR spreads the 128B row stride across all 32 banks (2-way max).
// EP: 0 -> Cout bf16 [N][M] (transposed, no bias)        (feeds next B^T)
//     1 -> Cout bf16 [M][N] = relu(acc + bias[n])        (feeds next A)
//     3 -> Cout fp32 [kc][M][N] = acc (split-K partial, no bias)
// ABF16: A is bf16 [M][K] (global_load_lds) vs fp32 [M][K] (reg-stage cvt).
// Klen: K-range per blockIdx.y chunk (koff = kc*Klen). gridDim.x % 8 == 0.
template <int EP, bool ABF16>
__global__ __launch_bounds__(256, 2)
void gemm_bt(const void* __restrict__ Av, const unsigned short* __restrict__ Bt,
             void* __restrict__ Cout, const float* __restrict__ bias,
             int M, int N, int K, int nbx, int Klen) {
  __shared__ __align__(16) unsigned short As[128 * 64];
  __shared__ __align__(16) unsigned short Bs[128 * 64];
  const int t = threadIdx.x;
  const int l = t & 63;
  const int w = t >> 6;

  // T1: XCD-chunked swizzle (bijective since gridDim.x % 8 == 0)
  int wg = blockIdx.x;
  const int cpx = gridDim.x >> 3;
  wg = (wg & 7) * cpx + (wg >> 3);
  const int mb = wg / nbx, nb = wg % nbx;
  const int kc = blockIdx.y;
  const int koff = kc * Klen;

  const int wr = w >> 1, wc = w & 1;
  f32x4 acc[4][4] = {};

  // staging geometry: instr i writes LDS bytes [i*4096 + w*1024 + l*16, +16)
  //   -> row = i*32 + w*8 + (l>>3); swizzled source k0 = 8*((l&7)^(l>>3))
  const int srow = w * 8 + (l >> 3);
  const int sk0  = 8 * ((l & 7) ^ (l >> 3));
  const unsigned short* Bg = Bt + (size_t)(nb * 128 + srow) * K + koff + sk0;
  unsigned short* BsL = Bs + w * 512 + l * 8;
  unsigned short* AsL = As + w * 512 + l * 8;

  const unsigned short* Ag16 = nullptr;
  const float* Ag32 = nullptr;
  unsigned short* AsWr = nullptr;
  int ak = 0, axm = 0;
  if constexpr (ABF16) {
    Ag16 = (const unsigned short*)Av + (size_t)(mb * 128 + srow) * K + koff + sk0;
  } else {
    const int ar = t >> 1;
    ak = (t & 1) * 32;
    axm = (ar & 7) << 3;
    Ag32 = (const float*)Av + (size_t)(mb * 128 + ar) * K + koff + ak;
    AsWr = As + ar * 64;
  }

  const int fr = l & 15, fq = l >> 4;
  const int rxor = (fr & 7) << 3;

  const int steps = Klen >> 6;
  for (int kb = 0; kb < steps; ++kb) {
#pragma unroll
    for (int i = 0; i < 4; ++i)
      gload_lds16(Bg + (size_t)i * 32 * K, BsL + i * 2048);
    Bg += 64;
    if constexpr (ABF16) {
#pragma unroll
      for (int i = 0; i < 4; ++i)
        gload_lds16(Ag16 + (size_t)i * 32 * K, AsL + i * 2048);
      Ag16 += 64;
    } else {
#pragma unroll
      for (int q = 0; q < 4; ++q) {
        float4 c0 = ((const float4*)Ag32)[q * 2];
        float4 c1 = ((const float4*)Ag32)[q * 2 + 1];
        u16x8 v;
        v[0] = f2bf(c0.x); v[1] = f2bf(c0.y); v[2] = f2bf(c0.z); v[3] = f2bf(c0.w);
        v[4] = f2bf(c1.x); v[5] = f2bf(c1.y); v[6] = f2bf(c1.z); v[7] = f2bf(c1.w);
        *(u16x8*)&AsWr[(ak + q * 8) ^ axm] = v;
      }
      Ag32 += 64;
    }
    __syncthreads();

    bf16x8 af[2][4], bfr[2][4];
#pragma unroll
    for (int kk = 0; kk < 2; ++kk) {
#pragma unroll
      for (int mi = 0; mi < 4; ++mi) {
        int arow = wr * 64 + mi * 16 + fr;
        af[kk][mi] = *(const bf16x8*)&As[arow * 64 + ((kk * 32 + fq * 8) ^ rxor)];
      }
#pragma unroll
      for (int ni = 0; ni < 4; ++ni) {
        int brow = wc * 64 + ni * 16 + fr;
        bfr[kk][ni] = *(const bf16x8*)&Bs[brow * 64 + ((kk * 32 + fq * 8) ^ rxor)];
      }
    }
#pragma unroll
    for (int kk = 0; kk < 2; ++kk)
#pragma unroll
      for (int mi = 0; mi < 4; ++mi)
#pragma unroll
        for (int ni = 0; ni < 4; ++ni)
          acc[mi][ni] = __builtin_amdgcn_mfma_f32_16x16x32_bf16(af[kk][mi], bfr[kk][ni],
                                                                acc[mi][ni], 0, 0, 0);
    __syncthreads();
  }

  // epilogue: C/D layout (m89/m91-verified): col = lane&15, row = (lane>>4)*4+r
  const int r0 = fq * 4;
  const int c0 = fr;
  const int growb = mb * 128 + wr * 64 + r0;
  const int gcolb = nb * 128 + wc * 64 + c0;
  if constexpr (EP == 0) {
    unsigned short* Ct = (unsigned short*)Cout;  // [N][M] bf16
#pragma unroll
    for (int ni = 0; ni < 4; ++ni) {
      int col = gcolb + ni * 16;
#pragma unroll
      for (int mi = 0; mi < 4; ++mi) {
        int row = growb + mi * 16;
        f32x4 v = acc[mi][ni];
        u16x4 o;
        o[0] = f2bf(v[0]); o[1] = f2bf(v[1]); o[2] = f2bf(v[2]); o[3] = f2bf(v[3]);
        *(u16x4*)&Ct[(size_t)col * M + row] = o;
      }
    }
  } else if constexpr (EP == 1) {
    unsigned short* C = (unsigned short*)Cout;  // [M][N] bf16, relu(.+bias)
#pragma unroll
    for (int ni = 0; ni < 4; ++ni) {
      int col = gcolb + ni * 16;
      float b = bias[col];
#pragma unroll
      for (int mi = 0; mi < 4; ++mi) {
        int row = growb + mi * 16;
        f32x4 v = acc[mi][ni];
#pragma unroll
        for (int r = 0; r < 4; ++r)
          C[(size_t)(row + r) * N + col] = f2bf(fmaxf(v[r] + b, 0.0f));
      }
    }
  } else {  // EP == 3: split-K fp32 partial
    float* C = (float*)Cout + (size_t)kc * M * N;
#pragma unroll
    for (int ni = 0; ni < 4; ++ni) {
      int col = gcolb + ni * 16;
#pragma unroll
      for (int mi = 0; mi < 4; ++mi) {
        int row = growb + mi * 16;
        f32x4 v = acc[mi][ni];
#pragma unroll
        for (int r = 0; r < 4; ++r)
          C[(size_t)(row + r) * N + col] = v[r];
      }
    }
  }
}

// ------------------------------ head kernel --------------------------------
// Block: 64 pairs x 256 cols, 4 waves each owning a 64-col slab. BK=64.
// A-tile gathered from EMB (bf16 [16384][256]) via per-lane gload_lds sources.
// LDS: union{ {As 8K, Bs 32K}, hdn 64x264 } + wh2s -> 44 KiB total.
// Tail: 4 lanes per pair, 64-k slices, shfl_xor reduce.
__global__ __launch_bounds__(256, 2)
void head_kernel(const unsigned short* __restrict__ EMB, const int* __restrict__ tf,
                 const int* __restrict__ gi, const unsigned short* __restrict__ Wh1t,
                 const float* __restrict__ bh1, const float* __restrict__ Wh2,
                 const float* __restrict__ bh2, float* __restrict__ out, int P) {
  __shared__ __align__(16) union SU {
    struct { unsigned short As[64 * 64]; unsigned short Bs[256 * 64]; } s;
    unsigned short hdn[64 * 264];
  } u;
  __shared__ float wh2s[256 * 3];
  const int t = threadIdx.x, l = t & 63, w = t >> 6;
  const int pb = blockIdx.x;

  wh2s[t]       = Wh2[t];
  wh2s[t + 256] = Wh2[t + 256];
  wh2s[t + 512] = Wh2[t + 512];

  const int srow = w * 8 + (l >> 3);
  const int sk0  = 8 * ((l & 7) ^ (l >> 3));
  size_t tfo[2], gio[2];
#pragma unroll
  for (int i = 0; i < 2; ++i) {
    int p = pb * 64 + i * 32 + srow;
    if (p >= P) p = P - 1;                 // clamp (writes masked later)
    tfo[i] = (size_t)tf[p] * 256;
    gio[i] = (size_t)gi[p] * 256;
  }
  const unsigned short* BgB = Wh1t + (size_t)srow * 512 + sk0;
  unsigned short* AsL = u.s.As + w * 512 + l * 8;
  unsigned short* BsL = u.s.Bs + w * 512 + l * 8;

  const int fr = l & 15, fq = l >> 4;
  const int rxor = (fr & 7) << 3;

  f32x4 acc[4][4] = {};
  for (int kb = 0; kb < 8; ++kb) {
    const int klo = (kb & 3) * 64 + sk0;   // concat K: kb<4 = tf half, else gene
#pragma unroll
    for (int i = 0; i < 2; ++i)
      gload_lds16(EMB + ((kb < 4) ? tfo[i] : gio[i]) + klo, AsL + i * 2048);
#pragma unroll
    for (int i = 0; i < 8; ++i)
      gload_lds16(BgB + (size_t)i * 32 * 512 + kb * 64, BsL + i * 2048);
    __syncthreads();

    bf16x8 af[2][4], bfr[2][4];
#pragma unroll
    for (int kk = 0; kk < 2; ++kk) {
#pragma unroll
      for (int mi = 0; mi < 4; ++mi) {
        int arow = mi * 16 + fr;
        af[kk][mi] = *(const bf16x8*)&u.s.As[arow * 64 + ((kk * 32 + fq * 8) ^ rxor)];
      }
#pragma unroll
      for (int ni = 0; ni < 4; ++ni) {
        int brow = w * 64 + ni * 16 + fr;
        bfr[kk][ni] = *(const bf16x8*)&u.s.Bs[brow * 64 + ((kk * 32 + fq * 8) ^ rxor)];
      }
    }
#pragma unroll
    for (int kk = 0; kk < 2; ++kk)
#pragma unroll
      for (int mi = 0; mi < 4; ++mi)
#pragma unroll
        for (int ni = 0; ni < 4; ++ni)
          acc[mi][ni] = __builtin_amdgcn_mfma_f32_16x16x32_bf16(af[kk][mi], bfr[kk][ni],
                                                                acc[mi][ni], 0, 0, 0);
    __syncthreads();
  }

  // bias + exact GELU -> hdn[row][col], row stride 264 (16B-aligned rows)
  const int r0 = fq * 4, c0 = fr;
#pragma unroll
  for (int ni = 0; ni < 4; ++ni) {
    int col = w * 64 + ni * 16 + c0;
    float b = bh1[col];
#pragma unroll
    for (int mi = 0; mi < 4; ++mi) {
      int row = mi * 16 + r0;
      f32x4 v = acc[mi][ni];
#pragma unroll
      for (int r = 0; r < 4; ++r) {
        float xv = v[r] + b;
        float g = 0.5f * xv * (1.0f + erff(xv * 0.70710678118f));
        u.hdn[(row + r) * 264 + col] = f2bf(g);
      }
    }
  }
  __syncthreads();

  // logits: 4 lanes per pair, each sums a 64-k slice, shfl_xor reduce
  const int pl = w * 16 + (l >> 2);
  const int pg = pb * 64 + pl;
  const int ks = (l & 3) * 64;
  float a0 = 0.f, a1 = 0.f, a2 = 0.f;
  const unsigned short* hr = u.hdn + pl * 264 + ks;
#pragma unroll
  for (int kq = 0; kq < 8; ++kq) {
    u16x8 hv = *(const u16x8*)(hr + kq * 8);
#pragma unroll
    for (int j = 0; j < 8; ++j) {
      float h = bf2f(hv[j]);
      int k = ks + kq * 8 + j;
      a0 = fmaf(h, wh2s[k * 3 + 0], a0);
      a1 = fmaf(h, wh2s[k * 3 + 1], a1);
      a2 = fmaf(h, wh2s[k * 3 + 2], a2);
    }
  }
  a0 += __shfl_xor(a0, 1); a0 += __shfl_xor(a0, 2);
  a1 += __shfl_xor(a1, 1); a1 += __shfl_xor(a1, 2);
  a2 += __shfl_xor(a2, 1); a2 += __shfl_xor(a2, 2);
  if ((l & 3) == 0 && pg < P) {
    out[(size_t)pg * 3 + 0] = a0 + bh2[0];
    out[(size_t)pg * 3 + 1] = a1 + bh2[1];
    out[(size_t)pg * 3 + 2] = a2 + bh2[2];
  }
}

// ------------------------------- launcher ----------------------------------

extern "C" void kernel_launch(void* const* d_in, const int* in_sizes, int n_in,
                              void* d_out, int out_size, void* d_ws, size_t ws_size,
                              hipStream_t stream) {
  const float* x   = (const float*)d_in[0];
  const float* adj = (const float*)d_in[1];
  const int*   tf  = (const int*)d_in[2];
  const int*   gi  = (const int*)d_in[3];
  const float* W0  = (const float*)d_in[4];
  const float* b0  = (const float*)d_in[5];
  const float* W1  = (const float*)d_in[6];
  const float* b1  = (const float*)d_in[7];
  const float* W2  = (const float*)d_in[8];
  const float* b2  = (const float*)d_in[9];
  const float* Wh1 = (const float*)d_in[10];
  const float* bh1 = (const float*)d_in[11];
  const float* Wh2 = (const float*)d_in[12];
  const float* bh2 = (const float*)d_in[13];
  float* out = (float*)d_out;

  const int NN = 16384;
  const int P = in_sizes[2];  // 100000

  char* ws = (char*)d_ws;
  size_t off = 0;
  auto alloc = [&](size_t bytes) -> char* {
    char* p = ws + off;
    off += (bytes + 255) & ~(size_t)255;
    return p;
  };
  unsigned short* W0t  = (unsigned short*)alloc((size_t)512 * 1024 * 2);
  unsigned short* W1t  = (unsigned short*)alloc((size_t)512 * 512 * 2);
  unsigned short* W2t  = (unsigned short*)alloc((size_t)256 * 512 * 2);
  unsigned short* Wh1t = (unsigned short*)alloc((size_t)256 * 512 * 2);
  unsigned short* Tt   = (unsigned short*)alloc((size_t)512 * NN * 2);  // T0t/T1t/T2t
  unsigned short* H    = (unsigned short*)alloc((size_t)NN * 512 * 2);  // H0/H1 bf16
  unsigned short* EMB  = (unsigned short*)alloc((size_t)NN * 256 * 2);
  float*          Pp   = (float*)alloc((size_t)2 * NN * 256 * 4);       // split-K partials
  size_t base_end = off;

  bool useAdjB = false;
  unsigned short* adjb = nullptr;
  if (ws_size >= base_end + (size_t)NN * NN * 2) {
    adjb = (unsigned short*)alloc((size_t)NN * NN * 2);
    useAdjB = true;
  }

  // weight transpose+convert (tiny)
  tcvt_kernel<<<dim3((1024 * 512 + 255) / 256), 256, 0, stream>>>(W0, W0t, 1024, 512);
  tcvt_kernel<<<dim3((512 * 512 + 255) / 256), 256, 0, stream>>>(W1, W1t, 512, 512);
  tcvt_kernel<<<dim3((512 * 256 + 255) / 256), 256, 0, stream>>>(W2, W2t, 512, 256);
  tcvt_kernel<<<dim3((512 * 256 + 255) / 256), 256, 0, stream>>>(Wh1, Wh1t, 512, 256);
  if (useAdjB)
    cvt_bf16_kernel<<<4096, 256, 0, stream>>>(adj, adjb, (size_t)NN * NN);

  // G1: T0t = (x @ W0)^T                       [512][16384] bf16
  gemm_bt<0, false><<<dim3(512), 256, 0, stream>>>(x, W0t, Tt, nullptr,
                                                   NN, 512, 1024, 4, 1024);
  // G2: H0 = relu(adj @ T0 + b0)               [16384][512] bf16
  if (useAdjB)
    gemm_bt<1, true><<<dim3(512), 256, 0, stream>>>(adjb, Tt, H, b0,
                                                    NN, 512, NN, 4, NN);
  else
    gemm_bt<1, false><<<dim3(512), 256, 0, stream>>>(adj, Tt, H, b0,
                                                     NN, 512, NN, 4, NN);
  // G3: T1t = (H0 @ W1)^T
  gemm_bt<0, true><<<dim3(512), 256, 0, stream>>>(H, W1t, Tt, nullptr,
                                                  NN, 512, 512, 4, 512);
  // G4: H1 = relu(adj @ T1 + b1)
  if (useAdjB)
    gemm_bt<1, true><<<dim3(512), 256, 0, stream>>>(adjb, Tt, H, b1,
                                                    NN, 512, NN, 4, NN);
  else
    gemm_bt<1, false><<<dim3(512), 256, 0, stream>>>(adj, Tt, H, b1,
                                                     NN, 512, NN, 4, NN);
  // G5: T2t = (H1 @ W2)^T                      [256][16384] bf16
  gemm_bt<0, true><<<dim3(256), 256, 0, stream>>>(H, W2t, Tt, nullptr,
                                                  NN, 256, 512, 2, 512);
  // G6: Pp[kc] = adj[:, kc] @ T2[kc, :]        split-K=2 fp32 partials
  if (useAdjB)
    gemm_bt<3, true><<<dim3(256, 2), 256, 0, stream>>>(adjb, Tt, Pp, nullptr,
                                                       NN, 256, NN, 2, NN / 2);
  else
    gemm_bt<3, false><<<dim3(256, 2), 256, 0, stream>>>(adj, Tt, Pp, nullptr,
                                                        NN, 256, NN, 2, NN / 2);
  // EMB = Pp[0] + Pp[1] + b2                   [16384][256] bf16
  reduce2_kernel<<<dim3(4096), 256, 0, stream>>>(Pp, b2, EMB, NN * 256, 256);
  // head: gather + MLP + logits
  head_kernel<<<dim3((P + 63) / 64), 256, 0, stream>>>(EMB, tf, gi, Wh1t, bh1,
                                                       Wh2, bh2, out, P);
}